// Round 4
// baseline (256.321 us; speedup 1.0000x reference)
//
#include <hip/hip_runtime.h>
#include <hip/hip_cooperative_groups.h>
#include <stdint.h>

namespace cg = cooperative_groups;

#define BATCH 1024
#define DIM 768

typedef unsigned long long u64;
typedef __attribute__((ext_vector_type(8))) short short8;  // 8 bf16 = 4 VGPRs
typedef __attribute__((ext_vector_type(4))) float f32x4;

// Workspace layout (bytes):
//   [0]        u64   hashes[1024]           (8 KB)
//   [8192]     float rl[1024]               (4 KB)
//   [12288]    float acc; int counter       (fallback path only)
//   [16384]    ushort txt_hi[1024*768]      (1.5 MB)
//   [1589248]  ushort txt_lo[1024*768]      (1.5 MB)
//   [3162112]  float  logits[1024*1024]     (4 MB)
#define WS_RL      8192
#define WS_ACC     12288
#define WS_TXTHI   16384
#define WS_TXTLO   (16384 + 1572864)
#define WS_LOGITS  (16384 + 2 * 1572864)
#define WS_NEED    ((size_t)(16384 + 2 * 1572864 + 4194304))

// x = bf16(hi) + bf16(lo) + O(2^-17 |x|); product needs only hh+hl+lh.
__device__ __forceinline__ void split_bf16(float x, unsigned short& hi, unsigned short& lo) {
    unsigned int u = __float_as_uint(x);
    unsigned int hb = (u + 0x7FFFu + ((u >> 16) & 1u)) >> 16;  // RNE to bf16
    float hf = __uint_as_float(hb << 16);
    float r = x - hf;
    unsigned int ur = __float_as_uint(r);
    unsigned int lb = (ur + 0x7FFFu + ((ur >> 16) & 1u)) >> 16;
    hi = (unsigned short)hb;
    lo = (unsigned short)lb;
}

// ---------------------------------------------------------------------------
// Fused cooperative kernel: 512 blocks x 256 threads, 2 blocks/CU.
// P0: txt fp32 -> bf16 hi/lo (2 rows/block) + img row hashes (2 rows/block)
// P1: GEMM via mfma_f32_16x16x32_bf16, split-precision (hh + hl + lh).
//     Block tile: 16 rows x 128 cols. A (img tile) staged in LDS frag-order;
//     B frags read directly from txt_hi/txt_lo in L2 (16B/lane, line-covering).
// P2: per-row duplicate-label scan (hash + exact verify) + softmax -> rl[row]
// P3: block 0 reduces rl -> out[0]
// ---------------------------------------------------------------------------
__global__ __launch_bounds__(256, 2) void fused_kernel(
        const float* __restrict__ img, const float* __restrict__ txt,
        const float* __restrict__ scale_p, u64* __restrict__ hashes,
        float* __restrict__ rl, unsigned short* __restrict__ txt_hi,
        unsigned short* __restrict__ txt_lo, float* __restrict__ logits,
        float* __restrict__ out) {
    __shared__ unsigned short Ahi[16 * DIM];  // frag order: ((k>>3)*16+m)*8+(k&7)
    __shared__ unsigned short Alo[16 * DIM];  // 24 KB + 24 KB
    __shared__ float partial[4];
    cg::grid_group grid = cg::this_grid();
    const int tid  = threadIdx.x;
    const int wave = tid >> 6;
    const int lane = tid & 63;
    const int b    = blockIdx.x;

    // ---------------- P0: txt conversion + img hashes ----------------
    {
        const int r0 = b * 2;
#pragma unroll
        for (int r = 0; r < 2; ++r) {
            const float* tr = txt + (size_t)(r0 + r) * DIM;
            unsigned short* th = txt_hi + (size_t)(r0 + r) * DIM;
            unsigned short* tl = txt_lo + (size_t)(r0 + r) * DIM;
#pragma unroll
            for (int c = 0; c < 3; ++c) {
                const int k = tid + c * 256;
                unsigned short hi, lo;
                split_bf16(tr[k], hi, lo);
                th[k] = hi;
                tl[k] = lo;
            }
        }
        if (wave < 2) {
            const int row = r0 + wave;
            const float4* rp = (const float4*)(img + (size_t)row * DIM);
            u64 h = 0;
#pragma unroll
            for (int c = 0; c < 3; ++c) {
                float4 v = rp[c * 64 + lane];
                int p = c * 256 + lane * 4;
                h += ((u64)__float_as_uint(v.x) + 0x9E3779B97F4A7C15ULL) * (u64)(2 * p + 1);
                h += ((u64)__float_as_uint(v.y) + 0x9E3779B97F4A7C15ULL) * (u64)(2 * p + 3);
                h += ((u64)__float_as_uint(v.z) + 0x9E3779B97F4A7C15ULL) * (u64)(2 * p + 5);
                h += ((u64)__float_as_uint(v.w) + 0x9E3779B97F4A7C15ULL) * (u64)(2 * p + 7);
            }
#pragma unroll
            for (int m = 32; m; m >>= 1) h += __shfl_xor(h, m, 64);
            if (lane == 0) hashes[row] = h;
        }
    }
    grid.sync();

    // ---------------- P1: MFMA GEMM, 16 rows x 128 cols per block ----------------
    {
        const int row0 = (b >> 3) * 16;
        const int col0 = (b & 7) * 128;
        // Stage A tile (16 x 768) into LDS in A-frag order, hi/lo split.
        for (int m = 0; m < 16; ++m) {
            const float* ir = img + (size_t)(row0 + m) * DIM;
#pragma unroll
            for (int c = 0; c < 3; ++c) {
                const int k = tid + c * 256;
                unsigned short hi, lo;
                split_bf16(ir[k], hi, lo);
                const int idx = ((k >> 3) * 16 + m) * 8 + (k & 7);
                Ahi[idx] = hi;
                Alo[idx] = lo;
            }
        }
        __syncthreads();
        const int quad = lane >> 4;
        const int l15  = lane & 15;
        const int cw   = col0 + wave * 32;  // wave covers 2 col-tiles of 16
        const int boff0 = (cw + l15) * DIM + quad * 8;
        const int boff1 = boff0 + 16 * DIM;
        const int abase = (quad * 16 + l15) * 8;
        f32x4 acc0 = {0.f, 0.f, 0.f, 0.f};
        f32x4 acc1 = {0.f, 0.f, 0.f, 0.f};
#pragma unroll 2
        for (int kk = 0; kk < 24; ++kk) {
            const int ai = abase + kk * 512;
            short8 ahi = *(const short8*)&Ahi[ai];
            short8 alo = *(const short8*)&Alo[ai];
            const int k0 = kk * 32;
            short8 bh0 = *(const short8*)(txt_hi + boff0 + k0);
            short8 bl0 = *(const short8*)(txt_lo + boff0 + k0);
            short8 bh1 = *(const short8*)(txt_hi + boff1 + k0);
            short8 bl1 = *(const short8*)(txt_lo + boff1 + k0);
            acc0 = __builtin_amdgcn_mfma_f32_16x16x32_bf16(ahi, bh0, acc0, 0, 0, 0);
            acc1 = __builtin_amdgcn_mfma_f32_16x16x32_bf16(ahi, bh1, acc1, 0, 0, 0);
            acc0 = __builtin_amdgcn_mfma_f32_16x16x32_bf16(ahi, bl0, acc0, 0, 0, 0);
            acc1 = __builtin_amdgcn_mfma_f32_16x16x32_bf16(ahi, bl1, acc1, 0, 0, 0);
            acc0 = __builtin_amdgcn_mfma_f32_16x16x32_bf16(alo, bh0, acc0, 0, 0, 0);
            acc1 = __builtin_amdgcn_mfma_f32_16x16x32_bf16(alo, bh1, acc1, 0, 0, 0);
        }
        // C/D layout: col = lane&15, row = quad*4 + reg  [m89-verified]
        const float scale = scale_p[0];
#pragma unroll
        for (int r = 0; r < 4; ++r) {
            const int row = row0 + quad * 4 + r;
            logits[(size_t)row * BATCH + cw + l15]      = scale * acc0[r];
            logits[(size_t)row * BATCH + cw + 16 + l15] = scale * acc1[r];
        }
    }
    grid.sync();

    // ---------------- P2: labels + softmax for rows 2b, 2b+1 ----------------
    if (wave < 2) {
        const int j = b * 2 + wave;
        const u64 hj = hashes[j];
        int cand = BATCH;
        for (int i = lane; i < j; i += 64)
            if (hashes[i] == hj) { cand = i; break; }
        int label = j;
        for (;;) {
            int mm = cand;
#pragma unroll
            for (int s = 32; s; s >>= 1) mm = min(mm, __shfl_xor(mm, s, 64));
            if (mm >= j) break;
            const float4* rpm = (const float4*)(img + (size_t)mm * DIM);
            const float4* rpj = (const float4*)(img + (size_t)j * DIM);
            bool eq = true;
#pragma unroll
            for (int c = 0; c < 3; ++c) {
                float4 vm = rpm[c * 64 + lane];
                float4 vj = rpj[c * 64 + lane];
                eq = eq && (vm.x == vj.x) && (vm.y == vj.y) &&
                     (vm.z == vj.z) && (vm.w == vj.w);
            }
            if (__all(eq)) { label = mm; break; }
            if (cand == mm) {  // hash false positive: owning lane advances
                cand = BATCH;
                for (int i = mm + 64; i < j; i += 64)
                    if (hashes[i] == hj) { cand = i; break; }
            }
        }
        // softmax over row j (1024 logits, 16 per lane)
        const float4* lr = (const float4*)(logits + (size_t)j * BATCH);
        float4 f0 = lr[lane];
        float4 f1 = lr[64 + lane];
        float4 f2 = lr[128 + lane];
        float4 f3 = lr[192 + lane];
        float mx = fmaxf(fmaxf(fmaxf(f0.x, f0.y), fmaxf(f0.z, f0.w)),
                         fmaxf(fmaxf(f1.x, f1.y), fmaxf(f1.z, f1.w)));
        mx = fmaxf(mx, fmaxf(fmaxf(fmaxf(f2.x, f2.y), fmaxf(f2.z, f2.w)),
                             fmaxf(fmaxf(f3.x, f3.y), fmaxf(f3.z, f3.w))));
#pragma unroll
        for (int s = 32; s; s >>= 1) mx = fmaxf(mx, __shfl_xor(mx, s, 64));
        float sum = __expf(f0.x - mx) + __expf(f0.y - mx) + __expf(f0.z - mx) + __expf(f0.w - mx)
                  + __expf(f1.x - mx) + __expf(f1.y - mx) + __expf(f1.z - mx) + __expf(f1.w - mx)
                  + __expf(f2.x - mx) + __expf(f2.y - mx) + __expf(f2.z - mx) + __expf(f2.w - mx)
                  + __expf(f3.x - mx) + __expf(f3.y - mx) + __expf(f3.z - mx) + __expf(f3.w - mx);
#pragma unroll
        for (int s = 32; s; s >>= 1) sum += __shfl_xor(sum, s, 64);
        if (lane == 0) {
            const float lv = logits[(size_t)j * BATCH + label];
            rl[j] = -(lv - mx - __logf(sum));
        }
    }
    grid.sync();

    // ---------------- P3: block 0 reduces mean ----------------
    if (b == 0) {
        float s = rl[tid] + rl[tid + 256] + rl[tid + 512] + rl[tid + 768];
#pragma unroll
        for (int m = 32; m; m >>= 1) s += __shfl_xor(s, m, 64);
        if ((tid & 63) == 0) partial[tid >> 6] = s;
        __syncthreads();
        if (tid == 0)
            out[0] = (partial[0] + partial[1] + partial[2] + partial[3]) * (1.0f / BATCH);
    }
}

// ===========================================================================
// Fallback path (ws too small): R2 kernels, verified exact. Uses <16.5 KB ws.
// ===========================================================================
__global__ __launch_bounds__(256) void hash_kernel(const float* __restrict__ img,
                                                   float* __restrict__ acc,
                                                   int* __restrict__ counter,
                                                   u64* __restrict__ hashes) {
    if (blockIdx.x == 0 && threadIdx.x == 0) { *acc = 0.0f; *counter = 0; }
    const int wave = threadIdx.x >> 6;
    const int lane = threadIdx.x & 63;
    const int row  = blockIdx.x * 4 + wave;
    const float4* rp = (const float4*)(img + (size_t)row * DIM);
    u64 h = 0;
#pragma unroll
    for (int c = 0; c < 3; ++c) {
        float4 v = rp[c * 64 + lane];
        int p = c * 256 + lane * 4;
        h += ((u64)__float_as_uint(v.x) + 0x9E3779B97F4A7C15ULL) * (u64)(2 * p + 1);
        h += ((u64)__float_as_uint(v.y) + 0x9E3779B97F4A7C15ULL) * (u64)(2 * p + 3);
        h += ((u64)__float_as_uint(v.z) + 0x9E3779B97F4A7C15ULL) * (u64)(2 * p + 5);
        h += ((u64)__float_as_uint(v.w) + 0x9E3779B97F4A7C15ULL) * (u64)(2 * p + 7);
    }
#pragma unroll
    for (int m = 32; m; m >>= 1) h += __shfl_xor(h, m, 64);
    if (lane == 0) hashes[row] = h;
}

__global__ __launch_bounds__(1024, 4) void clip_main_kernel(
        const float* __restrict__ img, const float* __restrict__ txt,
        const float* __restrict__ scale_p, const u64* __restrict__ hashes,
        float* __restrict__ acc, int* __restrict__ counter,
        float* __restrict__ out) {
    __shared__ float logits[4 * BATCH];
    __shared__ int   labels_s[4];
    __shared__ float rl[4];
    const int tid  = threadIdx.x;
    const int wave = tid >> 6;
    const int lane = tid & 63;
    const int row0 = blockIdx.x * 4;
    const float scale = scale_p[0];
    float4 a[4][3];
#pragma unroll
    for (int r = 0; r < 4; ++r) {
        const float4* rp = (const float4*)(img + (size_t)(row0 + r) * DIM);
#pragma unroll
        for (int c = 0; c < 3; ++c) a[r][c] = rp[c * 64 + lane];
    }
    if (wave < 4) {
        const int j = row0 + wave;
        const u64 hj = hashes[j];
        int cand = BATCH;
        for (int i = lane; i < j; i += 64)
            if (hashes[i] == hj) { cand = i; break; }
        int label = j;
        for (;;) {
            int m = cand;
#pragma unroll
            for (int s = 32; s; s >>= 1) m = min(m, __shfl_xor(m, s, 64));
            if (m >= j) break;
            const float4* rpm = (const float4*)(img + (size_t)m * DIM);
            const float4* rpj = (const float4*)(img + (size_t)j * DIM);
            bool eq = true;
#pragma unroll
            for (int c = 0; c < 3; ++c) {
                float4 vm = rpm[c * 64 + lane];
                float4 vj = rpj[c * 64 + lane];
                eq = eq && (vm.x == vj.x) && (vm.y == vj.y) &&
                     (vm.z == vj.z) && (vm.w == vj.w);
            }
            if (__all(eq)) { label = m; break; }
            if (cand == m) {
                cand = BATCH;
                for (int i = m + 64; i < j; i += 64)
                    if (hashes[i] == hj) { cand = i; break; }
            }
        }
        if (lane == 0) labels_s[wave] = label;
    }
    const int c0 = wave * 64;
    for (int i = 0; i < 64; i += 2) {
        float s00, s01, s02, s03, s10, s11, s12, s13;
        {
            const float4* tp = (const float4*)(txt + (size_t)(c0 + i) * DIM);
            float4 t0 = tp[lane], t1 = tp[64 + lane], t2 = tp[128 + lane];
            s00 = a[0][0].x*t0.x + a[0][0].y*t0.y + a[0][0].z*t0.z + a[0][0].w*t0.w
                + a[0][1].x*t1.x + a[0][1].y*t1.y + a[0][1].z*t1.z + a[0][1].w*t1.w
                + a[0][2].x*t2.x + a[0][2].y*t2.y + a[0][2].z*t2.z + a[0][2].w*t2.w;
            s01 = a[1][0].x*t0.x + a[1][0].y*t0.y + a[1][0].z*t0.z + a[1][0].w*t0.w
                + a[1][1].x*t1.x + a[1][1].y*t1.y + a[1][1].z*t1.z + a[1][1].w*t1.w
                + a[1][2].x*t2.x + a[1][2].y*t2.y + a[1][2].z*t2.z + a[1][2].w*t2.w;
            s02 = a[2][0].x*t0.x + a[2][0].y*t0.y + a[2][0].z*t0.z + a[2][0].w*t0.w
                + a[2][1].x*t1.x + a[2][1].y*t1.y + a[2][1].z*t1.z + a[2][1].w*t1.w
                + a[2][2].x*t2.x + a[2][2].y*t2.y + a[2][2].z*t2.z + a[2][2].w*t2.w;
            s03 = a[3][0].x*t0.x + a[3][0].y*t0.y + a[3][0].z*t0.z + a[3][0].w*t0.w
                + a[3][1].x*t1.x + a[3][1].y*t1.y + a[3][1].z*t1.z + a[3][1].w*t1.w
                + a[3][2].x*t2.x + a[3][2].y*t2.y + a[3][2].z*t2.z + a[3][2].w*t2.w;
        }
        {
            const float4* tp = (const float4*)(txt + (size_t)(c0 + i + 1) * DIM);
            float4 t0 = tp[lane], t1 = tp[64 + lane], t2 = tp[128 + lane];
            s10 = a[0][0].x*t0.x + a[0][0].y*t0.y + a[0][0].z*t0.z + a[0][0].w*t0.w
                + a[0][1].x*t1.x + a[0][1].y*t1.y + a[0][1].z*t1.z + a[0][1].w*t1.w
                + a[0][2].x*t2.x + a[0][2].y*t2.y + a[0][2].z*t2.z + a[0][2].w*t2.w;
            s11 = a[1][0].x*t0.x + a[1][0].y*t0.y + a[1][0].z*t0.z + a[1][0].w*t0.w
                + a[1][1].x*t1.x + a[1][1].y*t1.y + a[1][1].z*t1.z + a[1][1].w*t1.w
                + a[1][2].x*t2.x + a[1][2].y*t2.y + a[1][2].z*t2.z + a[1][2].w*t2.w;
            s12 = a[2][0].x*t0.x + a[2][0].y*t0.y + a[2][0].z*t0.z + a[2][0].w*t0.w
                + a[2][1].x*t1.x + a[2][1].y*t1.y + a[2][1].z*t1.z + a[2][1].w*t1.w
                + a[2][2].x*t2.x + a[2][2].y*t2.y + a[2][2].z*t2.z + a[2][2].w*t2.w;
            s13 = a[3][0].x*t0.x + a[3][0].y*t0.y + a[3][0].z*t0.z + a[3][0].w*t0.w
                + a[3][1].x*t1.x + a[3][1].y*t1.y + a[3][1].z*t1.z + a[3][1].w*t1.w
                + a[3][2].x*t2.x + a[3][2].y*t2.y + a[3][2].z*t2.z + a[3][2].w*t2.w;
        }
#pragma unroll
        for (int m = 32; m; m >>= 1) {
            s00 += __shfl_xor(s00, m, 64); s01 += __shfl_xor(s01, m, 64);
            s02 += __shfl_xor(s02, m, 64); s03 += __shfl_xor(s03, m, 64);
            s10 += __shfl_xor(s10, m, 64); s11 += __shfl_xor(s11, m, 64);
            s12 += __shfl_xor(s12, m, 64); s13 += __shfl_xor(s13, m, 64);
        }
        float v = s00;
        v = (lane == 1) ? s01 : v; v = (lane == 2) ? s02 : v; v = (lane == 3) ? s03 : v;
        v = (lane == 4) ? s10 : v; v = (lane == 5) ? s11 : v; v = (lane == 6) ? s12 : v;
        v = (lane == 7) ? s13 : v;
        if (lane < 8) {
            const int u = lane >> 2;
            const int r = lane & 3;
            logits[r * BATCH + c0 + i + u] = scale * v;
        }
    }
    __syncthreads();
    if (wave < 4) {
        const float4* lr = (const float4*)&logits[wave * BATCH];
        float v[16];
        float m = -INFINITY;
#pragma unroll
        for (int c = 0; c < 4; ++c) {
            float4 f = lr[c * 64 + lane];
            v[4*c+0] = f.x; v[4*c+1] = f.y; v[4*c+2] = f.z; v[4*c+3] = f.w;
            m = fmaxf(m, fmaxf(fmaxf(f.x, f.y), fmaxf(f.z, f.w)));
        }
#pragma unroll
        for (int s = 32; s; s >>= 1) m = fmaxf(m, __shfl_xor(m, s, 64));
        float sum = 0.0f;
#pragma unroll
        for (int k = 0; k < 16; ++k) sum += __expf(v[k] - m);
#pragma unroll
        for (int s = 32; s; s >>= 1) sum += __shfl_xor(sum, s, 64);
        if (lane == 0) {
            const float lv = logits[wave * BATCH + labels_s[wave]];
            rl[wave] = -(lv - m - __logf(sum));
        }
    }
    __syncthreads();
    if (tid == 0) {
        const float part = rl[0] + rl[1] + rl[2] + rl[3];
        atomicAdd(acc, part);
        __threadfence();
        const int old = atomicAdd(counter, 1);
        if (old == (int)gridDim.x - 1) {
            __threadfence();
            out[0] = (*(volatile float*)acc) * (1.0f / BATCH);
        }
    }
}

extern "C" void kernel_launch(void* const* d_in, const int* in_sizes, int n_in,
                              void* d_out, int out_size, void* d_ws, size_t ws_size,
                              hipStream_t stream) {
    const float* img   = (const float*)d_in[0];
    const float* txt   = (const float*)d_in[1];
    const float* scale = (const float*)d_in[2];
    float* out = (float*)d_out;
    char* ws = (char*)d_ws;

    u64*   hashes  = (u64*)ws;
    float* rl      = (float*)(ws + WS_RL);
    float* acc     = (float*)(ws + WS_ACC);
    int*   counter = (int*)(ws + WS_ACC + 4);
    unsigned short* txt_hi = (unsigned short*)(ws + WS_TXTHI);
    unsigned short* txt_lo = (unsigned short*)(ws + WS_TXTLO);
    float* logits  = (float*)(ws + WS_LOGITS);

    if (ws_size >= WS_NEED) {
        void* args[] = {(void*)&img, (void*)&txt, (void*)&scale, (void*)&hashes,
                        (void*)&rl, (void*)&txt_hi, (void*)&txt_lo, (void*)&logits,
                        (void*)&out};
        hipLaunchCooperativeKernel((void*)fused_kernel, dim3(512), dim3(256),
                                   args, 0, stream);
    } else {
        hash_kernel<<<256, 256, 0, stream>>>(img, acc, counter, hashes);
        clip_main_kernel<<<256, 1024, 0, stream>>>(img, txt, scale, hashes, acc,
                                                   counter, out);
    }
}

// Round 5
// 163.335 us; speedup vs baseline: 1.5693x; 1.5693x over previous
//
#include <hip/hip_runtime.h>
#include <stdint.h>

#define BATCH 1024
#define DIM 768

typedef unsigned long long u64;
typedef __attribute__((ext_vector_type(8))) short short8;  // 8 bf16 = 4 VGPRs
typedef __attribute__((ext_vector_type(4))) float f32x4;

// Workspace layout (bytes):
//   [0]       u64   hashes[1024]         (8 KB)
//   [8192]    float acc; int counter
//   [16384]   ushort txt_hi[1024*768]    (1.5 MB)
//   [1589248] ushort txt_lo[1024*768]    (1.5 MB)
// total ~3.1 MB (R3 proved ws_size >= 7.1 MB, so this fits).
#define WS_ACC   8192
#define WS_TXTHI 16384
#define WS_TXTLO (16384 + 1572864)

// x = bf16(hi) + bf16(lo) + O(2^-17 |x|); product needs only hh+hl+lh.
__device__ __forceinline__ void split_bf16(float x, unsigned short& hi, unsigned short& lo) {
    unsigned int u = __float_as_uint(x);
    unsigned int hb = (u + 0x7FFFu + ((u >> 16) & 1u)) >> 16;  // RNE to bf16
    float hf = __uint_as_float(hb << 16);
    float r = x - hf;
    unsigned int ur = __float_as_uint(r);
    unsigned int lb = (ur + 0x7FFFu + ((ur >> 16) & 1u)) >> 16;
    hi = (unsigned short)hb;
    lo = (unsigned short)lb;
}

// ---------------------------------------------------------------------------
// K1: txt fp32 -> bf16 hi/lo + img row hashes + zero accumulators.
// 256 blocks x 256 threads; wave w of block b handles row b*4+w for both jobs.
// ---------------------------------------------------------------------------
__global__ __launch_bounds__(256) void prep_kernel(
        const float* __restrict__ img, const float* __restrict__ txt,
        u64* __restrict__ hashes, float* __restrict__ acc, int* __restrict__ counter,
        unsigned short* __restrict__ txt_hi, unsigned short* __restrict__ txt_lo) {
    if (blockIdx.x == 0 && threadIdx.x == 0) { *acc = 0.0f; *counter = 0; }
    const int wave = threadIdx.x >> 6;
    const int lane = threadIdx.x & 63;
    const int row  = blockIdx.x * 4 + wave;

    // txt conversion (coalesced 4B loads, 2B stores)
    const float* tr = txt + (size_t)row * DIM;
    unsigned short* th = txt_hi + (size_t)row * DIM;
    unsigned short* tl = txt_lo + (size_t)row * DIM;
#pragma unroll
    for (int j = 0; j < 12; ++j) {
        const int k = lane + j * 64;
        unsigned short hi, lo;
        split_bf16(tr[k], hi, lo);
        th[k] = hi;
        tl[k] = lo;
    }

    // img row hash (order-independent positional hash; exact-verify later)
    const float4* rp = (const float4*)(img + (size_t)row * DIM);
    u64 h = 0;
#pragma unroll
    for (int c = 0; c < 3; ++c) {
        float4 v = rp[c * 64 + lane];
        int p = c * 256 + lane * 4;
        h += ((u64)__float_as_uint(v.x) + 0x9E3779B97F4A7C15ULL) * (u64)(2 * p + 1);
        h += ((u64)__float_as_uint(v.y) + 0x9E3779B97F4A7C15ULL) * (u64)(2 * p + 3);
        h += ((u64)__float_as_uint(v.z) + 0x9E3779B97F4A7C15ULL) * (u64)(2 * p + 5);
        h += ((u64)__float_as_uint(v.w) + 0x9E3779B97F4A7C15ULL) * (u64)(2 * p + 7);
    }
#pragma unroll
    for (int m = 32; m; m >>= 1) h += __shfl_xor(h, m, 64);
    if (lane == 0) hashes[row] = h;
}

// ---------------------------------------------------------------------------
// K2: MFMA GEMM + labels + softmax + reduce. 64 blocks x 1024 threads.
// Block = 16 rows x 1024 cols (one MFMA M-tile -> softmax stays block-local).
// LDS: A hi/lo tiles (48 KB) aliased with the 16x1024 fp32 logits (64 KB);
// barrier-separated. All MFMA layouts identical to the R3 kernel (absmax 0.0).
// ---------------------------------------------------------------------------
__global__ __launch_bounds__(1024) void gemm_loss_kernel(
        const float* __restrict__ img, const float* __restrict__ scale_p,
        const u64* __restrict__ hashes,
        const unsigned short* __restrict__ txt_hi,
        const unsigned short* __restrict__ txt_lo,
        float* __restrict__ acc, int* __restrict__ counter,
        float* __restrict__ out) {
    __shared__ char smem[65536];  // 64 KB total (per-workgroup LDS cap)
    unsigned short* Ahi = (unsigned short*)smem;            // 24 KB
    unsigned short* Alo = (unsigned short*)(smem + 24576);  // 24 KB
    float* logitsS = (float*)smem;                          // 64 KB, after k-loop

    const int tid  = threadIdx.x;
    const int wave = tid >> 6;
    const int lane = tid & 63;
    const int quad = lane >> 4;
    const int l15  = lane & 15;
    const int row0 = blockIdx.x * 16;

    // ---- stage A: wave w splits img row row0+w into LDS frag order ----
    {
        const float* ir = img + (size_t)(row0 + wave) * DIM;
#pragma unroll
        for (int j = 0; j < 12; ++j) {
            const int k = lane + j * 64;
            unsigned short hi, lo;
            split_bf16(ir[k], hi, lo);
            const int idx = ((k >> 3) * 16 + wave) * 8 + (k & 7);
            Ahi[idx] = hi;
            Alo[idx] = lo;
        }
    }
    __syncthreads();

    // ---- MFMA k-loop: wave covers cols [wave*64, wave*64+64), 4 tiles ----
    const int cw = wave * 64;
    const int b0 = (cw + l15) * DIM + quad * 8;
    const int b1 = b0 + 16 * DIM;
    const int b2 = b0 + 32 * DIM;
    const int b3 = b0 + 48 * DIM;
    const int abase = quad * 128 + l15 * 8;
    f32x4 acc0 = {0.f, 0.f, 0.f, 0.f};
    f32x4 acc1 = {0.f, 0.f, 0.f, 0.f};
    f32x4 acc2 = {0.f, 0.f, 0.f, 0.f};
    f32x4 acc3 = {0.f, 0.f, 0.f, 0.f};
#pragma unroll 2
    for (int kk = 0; kk < 24; ++kk) {
        const short8 ahi = *(const short8*)&Ahi[abase + kk * 512];
        const short8 alo = *(const short8*)&Alo[abase + kk * 512];
        const int ko = kk * 32;
        const short8 bh0 = *(const short8*)(txt_hi + b0 + ko);
        const short8 bl0 = *(const short8*)(txt_lo + b0 + ko);
        const short8 bh1 = *(const short8*)(txt_hi + b1 + ko);
        const short8 bl1 = *(const short8*)(txt_lo + b1 + ko);
        const short8 bh2 = *(const short8*)(txt_hi + b2 + ko);
        const short8 bl2 = *(const short8*)(txt_lo + b2 + ko);
        const short8 bh3 = *(const short8*)(txt_hi + b3 + ko);
        const short8 bl3 = *(const short8*)(txt_lo + b3 + ko);
        acc0 = __builtin_amdgcn_mfma_f32_16x16x32_bf16(ahi, bh0, acc0, 0, 0, 0);
        acc1 = __builtin_amdgcn_mfma_f32_16x16x32_bf16(ahi, bh1, acc1, 0, 0, 0);
        acc2 = __builtin_amdgcn_mfma_f32_16x16x32_bf16(ahi, bh2, acc2, 0, 0, 0);
        acc3 = __builtin_amdgcn_mfma_f32_16x16x32_bf16(ahi, bh3, acc3, 0, 0, 0);
        acc0 = __builtin_amdgcn_mfma_f32_16x16x32_bf16(ahi, bl0, acc0, 0, 0, 0);
        acc1 = __builtin_amdgcn_mfma_f32_16x16x32_bf16(ahi, bl1, acc1, 0, 0, 0);
        acc2 = __builtin_amdgcn_mfma_f32_16x16x32_bf16(ahi, bl2, acc2, 0, 0, 0);
        acc3 = __builtin_amdgcn_mfma_f32_16x16x32_bf16(ahi, bl3, acc3, 0, 0, 0);
        acc0 = __builtin_amdgcn_mfma_f32_16x16x32_bf16(alo, bh0, acc0, 0, 0, 0);
        acc1 = __builtin_amdgcn_mfma_f32_16x16x32_bf16(alo, bh1, acc1, 0, 0, 0);
        acc2 = __builtin_amdgcn_mfma_f32_16x16x32_bf16(alo, bh2, acc2, 0, 0, 0);
        acc3 = __builtin_amdgcn_mfma_f32_16x16x32_bf16(alo, bh3, acc3, 0, 0, 0);
    }
    __syncthreads();  // everyone done reading A -> safe to alias LDS

    // ---- write logits tile to LDS (C layout: col=l15, row=quad*4+r) ----
    const float scale = scale_p[0];
#pragma unroll
    for (int r = 0; r < 4; ++r) {
        const int rr = (quad * 4 + r) * BATCH;
        logitsS[rr + cw + l15]      = scale * acc0[r];
        logitsS[rr + cw + 16 + l15] = scale * acc1[r];
        logitsS[rr + cw + 32 + l15] = scale * acc2[r];
        logitsS[rr + cw + 48 + l15] = scale * acc3[r];
    }
    __syncthreads();

    // ---- wave w: duplicate label + softmax for row j = row0 + w ----
    {
        const int j = row0 + wave;
        const u64 hj = hashes[j];
        int cand = BATCH;  // per-lane first hash-matching index (stride 64)
        for (int i = lane; i < j; i += 64)
            if (hashes[i] == hj) { cand = i; break; }
        int label = j;
        for (;;) {
            int mm = cand;
#pragma unroll
            for (int s = 32; s; s >>= 1) mm = min(mm, __shfl_xor(mm, s, 64));
            if (mm >= j) break;
            const float4* rpm = (const float4*)(img + (size_t)mm * DIM);
            const float4* rpj = (const float4*)(img + (size_t)j * DIM);
            bool eq = true;
#pragma unroll
            for (int c = 0; c < 3; ++c) {
                float4 vm = rpm[c * 64 + lane];
                float4 vj = rpj[c * 64 + lane];
                eq = eq && (vm.x == vj.x) && (vm.y == vj.y) &&
                     (vm.z == vj.z) && (vm.w == vj.w);
            }
            if (__all(eq)) { label = mm; break; }
            if (cand == mm) {  // hash false positive: owning lane advances
                cand = BATCH;
                for (int i = mm + 64; i < j; i += 64)
                    if (hashes[i] == hj) { cand = i; break; }
            }
        }

        const float4* lr4 = (const float4*)(logitsS + wave * BATCH);
        float4 f0 = lr4[lane];
        float4 f1 = lr4[64 + lane];
        float4 f2 = lr4[128 + lane];
        float4 f3 = lr4[192 + lane];
        float mx = fmaxf(fmaxf(fmaxf(f0.x, f0.y), fmaxf(f0.z, f0.w)),
                         fmaxf(fmaxf(f1.x, f1.y), fmaxf(f1.z, f1.w)));
        mx = fmaxf(mx, fmaxf(fmaxf(fmaxf(f2.x, f2.y), fmaxf(f2.z, f2.w)),
                             fmaxf(fmaxf(f3.x, f3.y), fmaxf(f3.z, f3.w))));
#pragma unroll
        for (int s = 32; s; s >>= 1) mx = fmaxf(mx, __shfl_xor(mx, s, 64));
        float sum = __expf(f0.x - mx) + __expf(f0.y - mx) + __expf(f0.z - mx) + __expf(f0.w - mx)
                  + __expf(f1.x - mx) + __expf(f1.y - mx) + __expf(f1.z - mx) + __expf(f1.w - mx)
                  + __expf(f2.x - mx) + __expf(f2.y - mx) + __expf(f2.z - mx) + __expf(f2.w - mx)
                  + __expf(f3.x - mx) + __expf(f3.y - mx) + __expf(f3.z - mx) + __expf(f3.w - mx);
#pragma unroll
        for (int s = 32; s; s >>= 1) sum += __shfl_xor(sum, s, 64);
        if (lane == 0) {
            const float lv = logitsS[wave * BATCH + label];
            atomicAdd(acc, -(lv - mx - __logf(sum)));
        }
    }
    __syncthreads();

    // ---- last block writes the mean ----
    if (tid == 0) {
        __threadfence();
        const int old = atomicAdd(counter, 1);
        if (old == (int)gridDim.x - 1) {
            __threadfence();
            out[0] = (*(volatile float*)acc) * (1.0f / BATCH);
        }
    }
}

extern "C" void kernel_launch(void* const* d_in, const int* in_sizes, int n_in,
                              void* d_out, int out_size, void* d_ws, size_t ws_size,
                              hipStream_t stream) {
    const float* img   = (const float*)d_in[0];
    const float* txt   = (const float*)d_in[1];
    const float* scale = (const float*)d_in[2];
    float* out = (float*)d_out;
    char* ws = (char*)d_ws;

    u64*   hashes  = (u64*)ws;
    float* acc     = (float*)(ws + WS_ACC);
    int*   counter = (int*)(ws + WS_ACC + 4);
    unsigned short* txt_hi = (unsigned short*)(ws + WS_TXTHI);
    unsigned short* txt_lo = (unsigned short*)(ws + WS_TXTLO);

    prep_kernel<<<256, 256, 0, stream>>>(img, txt, hashes, acc, counter, txt_hi, txt_lo);
    gemm_loss_kernel<<<64, 1024, 0, stream>>>(img, scale, hashes, txt_hi, txt_lo,
                                              acc, counter, out);
}

// Round 6
// 108.407 us; speedup vs baseline: 2.3644x; 1.5067x over previous
//
#include <hip/hip_runtime.h>
#include <stdint.h>

#define BATCH 1024
#define DIM 768

typedef unsigned long long u64;
typedef __attribute__((ext_vector_type(8))) short short8;  // 8 bf16 = 4 VGPRs
typedef __attribute__((ext_vector_type(4))) float f32x4;

// Workspace layout (bytes):
//   [0]       u64   hashes[1024]         (8 KB)
//   [8192]    float acc; int counter
//   [16384]   ushort txtB_hi[1024*768]   (1.5 MB)  -- MFMA B-frag order
//   [1589248] ushort txtB_lo[1024*768]   (1.5 MB)
// B-frag order: off(col,k) = ((k>>5)*64 + (col>>4))*512 + ((k>>3)&3)*128
//                            + (col&15)*8 + (k&7)
// so a wave's 16x16x32 B-fragment (16 cols x 32 k) is one contiguous 1 KB run.
#define WS_ACC   8192
#define WS_TXTHI 16384
#define WS_TXTLO (16384 + 1572864)

// x = bf16(hi) + bf16(lo) + O(2^-17 |x|); product needs only hh+hl+lh.
__device__ __forceinline__ void split_bf16(float x, unsigned short& hi, unsigned short& lo) {
    unsigned int u = __float_as_uint(x);
    unsigned int hb = (u + 0x7FFFu + ((u >> 16) & 1u)) >> 16;  // RNE to bf16
    float hf = __uint_as_float(hb << 16);
    float r = x - hf;
    unsigned int ur = __float_as_uint(r);
    unsigned int lb = (ur + 0x7FFFu + ((ur >> 16) & 1u)) >> 16;
    hi = (unsigned short)hb;
    lo = (unsigned short)lb;
}

// ---------------------------------------------------------------------------
// K1: txt fp32 -> bf16 hi/lo in B-frag order + img row hashes + zero acc.
// 256 blocks x 256 threads; wave w of block b handles row b*4+w.
// Loads coalesced (32 B/lane); stores are 16 B frag-chunks (L2-absorbed).
// ---------------------------------------------------------------------------
__global__ __launch_bounds__(256) void prep_kernel(
        const float* __restrict__ img, const float* __restrict__ txt,
        u64* __restrict__ hashes, float* __restrict__ acc, int* __restrict__ counter,
        unsigned short* __restrict__ txtB_hi, unsigned short* __restrict__ txtB_lo) {
    if (blockIdx.x == 0 && threadIdx.x == 0) { *acc = 0.0f; *counter = 0; }
    const int wave = threadIdx.x >> 6;
    const int lane = threadIdx.x & 63;
    const int row  = blockIdx.x * 4 + wave;  // = col of B
    const int ctile = row >> 4;
    const int l15c  = row & 15;

    const float* tr = txt + (size_t)row * DIM;
    // 96 chunks of 8 k-values; lane handles chunks lane and lane+64 (32 idle ok)
    for (int c2 = lane; c2 < 96; c2 += 64) {
        const int k0 = c2 * 8;
        const float4 va = *(const float4*)(tr + k0);
        const float4 vb = *(const float4*)(tr + k0 + 4);
        unsigned short h0,h1,h2,h3,h4,h5,h6,h7, l0,l1,l2,l3,l4,l5,l6,l7;
        split_bf16(va.x, h0, l0); split_bf16(va.y, h1, l1);
        split_bf16(va.z, h2, l2); split_bf16(va.w, h3, l3);
        split_bf16(vb.x, h4, l4); split_bf16(vb.y, h5, l5);
        split_bf16(vb.z, h6, l6); split_bf16(vb.w, h7, l7);
        const size_t off = (size_t)((c2 >> 2) * 64 + ctile) * 512
                         + (size_t)(c2 & 3) * 128 + l15c * 8;
        short8 hv = {(short)h0,(short)h1,(short)h2,(short)h3,
                     (short)h4,(short)h5,(short)h6,(short)h7};
        short8 lv = {(short)l0,(short)l1,(short)l2,(short)l3,
                     (short)l4,(short)l5,(short)l6,(short)l7};
        *(short8*)(txtB_hi + off) = hv;
        *(short8*)(txtB_lo + off) = lv;
    }

    // img row hash (order-independent positional hash; exact-verify later)
    const float4* rp = (const float4*)(img + (size_t)row * DIM);
    u64 h = 0;
#pragma unroll
    for (int c = 0; c < 3; ++c) {
        float4 v = rp[c * 64 + lane];
        int p = c * 256 + lane * 4;
        h += ((u64)__float_as_uint(v.x) + 0x9E3779B97F4A7C15ULL) * (u64)(2 * p + 1);
        h += ((u64)__float_as_uint(v.y) + 0x9E3779B97F4A7C15ULL) * (u64)(2 * p + 3);
        h += ((u64)__float_as_uint(v.z) + 0x9E3779B97F4A7C15ULL) * (u64)(2 * p + 5);
        h += ((u64)__float_as_uint(v.w) + 0x9E3779B97F4A7C15ULL) * (u64)(2 * p + 7);
    }
#pragma unroll
    for (int m = 32; m; m >>= 1) h += __shfl_xor(h, m, 64);
    if (lane == 0) hashes[row] = h;
}

// ---------------------------------------------------------------------------
// K2: MFMA GEMM + labels + softmax + reduce. 64 blocks x 1024 threads.
// Block = 16 rows x 1024 cols (one MFMA M-tile -> softmax stays block-local).
// B-frag loads are now contiguous 1 KB per wave (coalesced 16 B/lane).
// LDS: A hi/lo (48 KB) aliased with 16x1024 fp32 logits (64 KB), barriered.
// ---------------------------------------------------------------------------
__global__ __launch_bounds__(1024) void gemm_loss_kernel(
        const float* __restrict__ img, const float* __restrict__ scale_p,
        const u64* __restrict__ hashes,
        const unsigned short* __restrict__ txtB_hi,
        const unsigned short* __restrict__ txtB_lo,
        float* __restrict__ acc, int* __restrict__ counter,
        float* __restrict__ out) {
    __shared__ char smem[65536];  // 64 KB
    unsigned short* Ahi = (unsigned short*)smem;            // 24 KB
    unsigned short* Alo = (unsigned short*)(smem + 24576);  // 24 KB
    float* logitsS = (float*)smem;                          // 64 KB, after k-loop

    const int tid  = threadIdx.x;
    const int wave = tid >> 6;
    const int lane = tid & 63;
    const int quad = lane >> 4;
    const int l15  = lane & 15;
    const int row0 = blockIdx.x * 16;

    // ---- stage A: wave w splits img row row0+w into LDS frag order ----
    {
        const float* ir = img + (size_t)(row0 + wave) * DIM;
#pragma unroll
        for (int j = 0; j < 12; ++j) {
            const int k = lane + j * 64;
            unsigned short hi, lo;
            split_bf16(ir[k], hi, lo);
            const int idx = ((k >> 3) * 16 + wave) * 8 + (k & 7);
            Ahi[idx] = hi;
            Alo[idx] = lo;
        }
    }
    __syncthreads();

    // ---- MFMA k-loop: wave covers col-tiles tb..tb+3 (cols wave*64..+63) ----
    const int tb = wave * 4;
    const int frag_off = quad * 128 + l15 * 8;  // within a 512-short frag block
    const int abase = frag_off;                 // A-frag: same lane offset
    f32x4 acc0 = {0.f, 0.f, 0.f, 0.f};
    f32x4 acc1 = {0.f, 0.f, 0.f, 0.f};
    f32x4 acc2 = {0.f, 0.f, 0.f, 0.f};
    f32x4 acc3 = {0.f, 0.f, 0.f, 0.f};
#pragma unroll 2
    for (int kk = 0; kk < 24; ++kk) {
        const short8 ahi = *(const short8*)&Ahi[abase + kk * 512];
        const short8 alo = *(const short8*)&Alo[abase + kk * 512];
        const size_t base = (size_t)(kk * 64 + tb) * 512 + frag_off;
        const short8 bh0 = *(const short8*)(txtB_hi + base);
        const short8 bl0 = *(const short8*)(txtB_lo + base);
        const short8 bh1 = *(const short8*)(txtB_hi + base + 512);
        const short8 bl1 = *(const short8*)(txtB_lo + base + 512);
        const short8 bh2 = *(const short8*)(txtB_hi + base + 1024);
        const short8 bl2 = *(const short8*)(txtB_lo + base + 1024);
        const short8 bh3 = *(const short8*)(txtB_hi + base + 1536);
        const short8 bl3 = *(const short8*)(txtB_lo + base + 1536);
        acc0 = __builtin_amdgcn_mfma_f32_16x16x32_bf16(ahi, bh0, acc0, 0, 0, 0);
        acc1 = __builtin_amdgcn_mfma_f32_16x16x32_bf16(ahi, bh1, acc1, 0, 0, 0);
        acc2 = __builtin_amdgcn_mfma_f32_16x16x32_bf16(ahi, bh2, acc2, 0, 0, 0);
        acc3 = __builtin_amdgcn_mfma_f32_16x16x32_bf16(ahi, bh3, acc3, 0, 0, 0);
        acc0 = __builtin_amdgcn_mfma_f32_16x16x32_bf16(ahi, bl0, acc0, 0, 0, 0);
        acc1 = __builtin_amdgcn_mfma_f32_16x16x32_bf16(ahi, bl1, acc1, 0, 0, 0);
        acc2 = __builtin_amdgcn_mfma_f32_16x16x32_bf16(ahi, bl2, acc2, 0, 0, 0);
        acc3 = __builtin_amdgcn_mfma_f32_16x16x32_bf16(ahi, bl3, acc3, 0, 0, 0);
        acc0 = __builtin_amdgcn_mfma_f32_16x16x32_bf16(alo, bh0, acc0, 0, 0, 0);
        acc1 = __builtin_amdgcn_mfma_f32_16x16x32_bf16(alo, bh1, acc1, 0, 0, 0);
        acc2 = __builtin_amdgcn_mfma_f32_16x16x32_bf16(alo, bh2, acc2, 0, 0, 0);
        acc3 = __builtin_amdgcn_mfma_f32_16x16x32_bf16(alo, bh3, acc3, 0, 0, 0);
    }
    __syncthreads();  // all waves done reading A -> safe to alias LDS

    // ---- write logits tile to LDS (C layout: col=l15, row=quad*4+r) ----
    const float scale = scale_p[0];
    const int cw = wave * 64;
#pragma unroll
    for (int r = 0; r < 4; ++r) {
        const int rr = (quad * 4 + r) * BATCH;
        logitsS[rr + cw + l15]      = scale * acc0[r];
        logitsS[rr + cw + 16 + l15] = scale * acc1[r];
        logitsS[rr + cw + 32 + l15] = scale * acc2[r];
        logitsS[rr + cw + 48 + l15] = scale * acc3[r];
    }
    __syncthreads();

    // ---- wave w: duplicate label + softmax for row j = row0 + w ----
    {
        const int j = row0 + wave;
        const u64 hj = hashes[j];
        int cand = BATCH;  // per-lane first hash-matching index (stride 64)
        for (int i = lane; i < j; i += 64)
            if (hashes[i] == hj) { cand = i; break; }
        int label = j;
        for (;;) {
            int mm = cand;
#pragma unroll
            for (int s = 32; s; s >>= 1) mm = min(mm, __shfl_xor(mm, s, 64));
            if (mm >= j) break;
            const float4* rpm = (const float4*)(img + (size_t)mm * DIM);
            const float4* rpj = (const float4*)(img + (size_t)j * DIM);
            bool eq = true;
#pragma unroll
            for (int c = 0; c < 3; ++c) {
                float4 vm = rpm[c * 64 + lane];
                float4 vj = rpj[c * 64 + lane];
                eq = eq && (vm.x == vj.x) && (vm.y == vj.y) &&
                     (vm.z == vj.z) && (vm.w == vj.w);
            }
            if (__all(eq)) { label = mm; break; }
            if (cand == mm) {  // hash false positive: owning lane advances
                cand = BATCH;
                for (int i = mm + 64; i < j; i += 64)
                    if (hashes[i] == hj) { cand = i; break; }
            }
        }

        const float4* lr4 = (const float4*)(logitsS + wave * BATCH);
        float4 f0 = lr4[lane];
        float4 f1 = lr4[64 + lane];
        float4 f2 = lr4[128 + lane];
        float4 f3 = lr4[192 + lane];
        float mx = fmaxf(fmaxf(fmaxf(f0.x, f0.y), fmaxf(f0.z, f0.w)),
                         fmaxf(fmaxf(f1.x, f1.y), fmaxf(f1.z, f1.w)));
        mx = fmaxf(mx, fmaxf(fmaxf(fmaxf(f2.x, f2.y), fmaxf(f2.z, f2.w)),
                             fmaxf(fmaxf(f3.x, f3.y), fmaxf(f3.z, f3.w))));
#pragma unroll
        for (int s = 32; s; s >>= 1) mx = fmaxf(mx, __shfl_xor(mx, s, 64));
        float sum = __expf(f0.x - mx) + __expf(f0.y - mx) + __expf(f0.z - mx) + __expf(f0.w - mx)
                  + __expf(f1.x - mx) + __expf(f1.y - mx) + __expf(f1.z - mx) + __expf(f1.w - mx)
                  + __expf(f2.x - mx) + __expf(f2.y - mx) + __expf(f2.z - mx) + __expf(f2.w - mx)
                  + __expf(f3.x - mx) + __expf(f3.y - mx) + __expf(f3.z - mx) + __expf(f3.w - mx);
#pragma unroll
        for (int s = 32; s; s >>= 1) sum += __shfl_xor(sum, s, 64);
        if (lane == 0) {
            const float lv = logitsS[wave * BATCH + label];
            atomicAdd(acc, -(lv - mx - __logf(sum)));
        }
    }
    __syncthreads();

    // ---- last block writes the mean ----
    if (tid == 0) {
        __threadfence();
        const int old = atomicAdd(counter, 1);
        if (old == (int)gridDim.x - 1) {
            __threadfence();
            out[0] = (*(volatile float*)acc) * (1.0f / BATCH);
        }
    }
}

extern "C" void kernel_launch(void* const* d_in, const int* in_sizes, int n_in,
                              void* d_out, int out_size, void* d_ws, size_t ws_size,
                              hipStream_t stream) {
    const float* img   = (const float*)d_in[0];
    const float* txt   = (const float*)d_in[1];
    const float* scale = (const float*)d_in[2];
    float* out = (float*)d_out;
    char* ws = (char*)d_ws;

    u64*   hashes  = (u64*)ws;
    float* acc     = (float*)(ws + WS_ACC);
    int*   counter = (int*)(ws + WS_ACC + 4);
    unsigned short* txtB_hi = (unsigned short*)(ws + WS_TXTHI);
    unsigned short* txtB_lo = (unsigned short*)(ws + WS_TXTLO);

    prep_kernel<<<256, 256, 0, stream>>>(img, txt, hashes, acc, counter, txtB_hi, txtB_lo);
    gemm_loss_kernel<<<64, 1024, 0, stream>>>(img, scale, hashes, txtB_hi, txtB_lo,
                                              acc, counter, out);
}

// Round 7
// 86.195 us; speedup vs baseline: 2.9737x; 1.2577x over previous
//
#include <hip/hip_runtime.h>
#include <stdint.h>

#define BATCH 1024
#define DIM 768

typedef unsigned long long u64;
typedef __attribute__((ext_vector_type(8))) short short8;  // 8 bf16 = 4 VGPRs
typedef __attribute__((ext_vector_type(4))) float f32x4;

// Workspace layout (bytes):
//   [0]      u64   hashes[1024]        (8 KB)
//   [8192]   float acc; int counter
//   [12288]  float pmax[1024*4]        (16 KB)  per-row per-chunk max
//   [28672]  float psum[1024*4]        (16 KB)  per-row per-chunk sumexp
//   [49152]  ushort txtB[1024*768]     (1.5 MB) bf16, MFMA B-frag order
// B-frag order: off(col,k) = ((k>>5)*64 + (col>>4))*512 + ((k>>3)&3)*128
//                            + (col&15)*8 + (k&7)
// -> a wave's 16x16x32 B-fragment is one contiguous 1 KB run (16 B/lane).
#define WS_ACC  8192
#define WS_PMAX 12288
#define WS_PSUM 28672
#define WS_TXTB 49152

__device__ __forceinline__ unsigned short to_bf16(float x) {
    unsigned int u = __float_as_uint(x);
    return (unsigned short)((u + 0x7FFFu + ((u >> 16) & 1u)) >> 16);  // RNE
}

// ---------------------------------------------------------------------------
// K1: txt fp32 -> bf16 B-frag order + img row hashes + zero acc/counter.
// 256 blocks x 256 threads. txt work: 64 tiles x 24 k-groups = 1536 groups,
// block b handles groups b*6..b*6+5 (split across its 4 waves). Each group:
// lane reads 32 B from txt row (tile*16 + (lane&15)), writes 16 B contiguous.
// Hash work: wave w hashes img row b*4+w.
// ---------------------------------------------------------------------------
__global__ __launch_bounds__(256) void prep_kernel(
        const float* __restrict__ img, const float* __restrict__ txt,
        u64* __restrict__ hashes, float* __restrict__ acc, int* __restrict__ counter,
        unsigned short* __restrict__ txtB) {
    if (blockIdx.x == 0 && threadIdx.x == 0) { *acc = 0.0f; *counter = 0; }
    const int wave = threadIdx.x >> 6;
    const int lane = threadIdx.x & 63;

    for (int i = wave; i < 6; i += 4) {
        const int G  = blockIdx.x * 6 + i;
        const int tt = G / 24;        // col-tile 0..63
        const int g  = G - tt * 24;   // k-group 0..23
        const int col = tt * 16 + (lane & 15);
        const int k0  = g * 32 + (lane >> 4) * 8;
        const float4 va = *(const float4*)(txt + (size_t)col * DIM + k0);
        const float4 vb = *(const float4*)(txt + (size_t)col * DIM + k0 + 4);
        short8 hv = {(short)to_bf16(va.x), (short)to_bf16(va.y),
                     (short)to_bf16(va.z), (short)to_bf16(va.w),
                     (short)to_bf16(vb.x), (short)to_bf16(vb.y),
                     (short)to_bf16(vb.z), (short)to_bf16(vb.w)};
        *(short8*)(txtB + (size_t)(g * 64 + tt) * 512 + lane * 8) = hv;
    }

    // img row hash (order-independent positional hash; exact-verify later)
    const int row = blockIdx.x * 4 + wave;
    const float4* rp = (const float4*)(img + (size_t)row * DIM);
    u64 h = 0;
#pragma unroll
    for (int c = 0; c < 3; ++c) {
        float4 v = rp[c * 64 + lane];
        int p = c * 256 + lane * 4;
        h += ((u64)__float_as_uint(v.x) + 0x9E3779B97F4A7C15ULL) * (u64)(2 * p + 1);
        h += ((u64)__float_as_uint(v.y) + 0x9E3779B97F4A7C15ULL) * (u64)(2 * p + 3);
        h += ((u64)__float_as_uint(v.z) + 0x9E3779B97F4A7C15ULL) * (u64)(2 * p + 5);
        h += ((u64)__float_as_uint(v.w) + 0x9E3779B97F4A7C15ULL) * (u64)(2 * p + 7);
    }
#pragma unroll
    for (int m = 32; m; m >>= 1) h += __shfl_xor(h, m, 64);
    if (lane == 0) hashes[row] = h;
}

// ---------------------------------------------------------------------------
// K2: MFMA GEMM + per-row per-chunk softmax partials. 256 blocks x 1024 thr.
// Block = 16 rows x 256 cols (row-group b>>2, col-chunk b&3). Wave w owns one
// 16-col tile: 24 MFMAs, B-frags contiguous from txtB. Per-row (wave w = row
// w) partial max + sumexp over its 256 cols -> pmax/psum[row*4+chunk].
// ---------------------------------------------------------------------------
__global__ __launch_bounds__(1024) void gemm_kernel(
        const float* __restrict__ img, const float* __restrict__ scale_p,
        const unsigned short* __restrict__ txtB,
        float* __restrict__ pmax, float* __restrict__ psum) {
    __shared__ unsigned short Ahi[16 * DIM];   // 24 KB, A-frag order
    __shared__ float logitsS[16 * 260];        // 16.6 KB (+4 pad vs bank stride)

    const int tid  = threadIdx.x;
    const int wave = tid >> 6;
    const int lane = tid & 63;
    const int quad = lane >> 4;
    const int l15  = lane & 15;
    const int r0    = (blockIdx.x >> 2) * 16;
    const int chunk = blockIdx.x & 3;

    // stage A: wave w converts img row r0+w into frag order
    {
        const float* ir = img + (size_t)(r0 + wave) * DIM;
#pragma unroll
        for (int j = 0; j < 12; ++j) {
            const int k = lane + j * 64;
            Ahi[((k >> 3) * 16 + wave) * 8 + (k & 7)] = to_bf16(ir[k]);
        }
    }
    __syncthreads();

    // k-loop: wave's global col-tile t, one MFMA per 32-k step
    const int t = chunk * 16 + wave;
    const int foff = quad * 128 + l15 * 8;
    f32x4 acc = {0.f, 0.f, 0.f, 0.f};
#pragma unroll
    for (int kk = 0; kk < 24; ++kk) {
        const short8 a = *(const short8*)&Ahi[kk * 512 + foff];
        const short8 b = *(const short8*)(txtB + (size_t)(kk * 64 + t) * 512 + foff);
        acc = __builtin_amdgcn_mfma_f32_16x16x32_bf16(a, b, acc, 0, 0, 0);
    }

    // C layout: col = l15, row = quad*4 + r  [verified R3-R5, absmax 0.0]
    const float scale = scale_p[0];
#pragma unroll
    for (int r = 0; r < 4; ++r)
        logitsS[(quad * 4 + r) * 260 + wave * 16 + l15] = scale * acc[r];
    __syncthreads();

    // per-row partials: wave w = row w; 4 floats/lane over 256 cols
    {
        const float4 f = *(const float4*)&logitsS[wave * 260 + lane * 4];
        float mx = fmaxf(fmaxf(f.x, f.y), fmaxf(f.z, f.w));
#pragma unroll
        for (int s = 32; s; s >>= 1) mx = fmaxf(mx, __shfl_xor(mx, s, 64));
        float sum = __expf(f.x - mx) + __expf(f.y - mx) +
                    __expf(f.z - mx) + __expf(f.w - mx);
#pragma unroll
        for (int s = 32; s; s >>= 1) sum += __shfl_xor(sum, s, 64);
        if (lane == 0) {
            pmax[(r0 + wave) * 4 + chunk] = mx;
            psum[(r0 + wave) * 4 + chunk] = sum;
        }
    }
}

// ---------------------------------------------------------------------------
// K3: labels + exact fp32 label-logit + chunk combine + mean. 64 blocks x
// 1024 threads; wave w owns row j = blockIdx*16 + w.
// ---------------------------------------------------------------------------
__global__ __launch_bounds__(1024) void final_kernel(
        const float* __restrict__ img, const float* __restrict__ txt,
        const float* __restrict__ scale_p, const u64* __restrict__ hashes,
        const float* __restrict__ pmax, const float* __restrict__ psum,
        float* __restrict__ acc, int* __restrict__ counter,
        float* __restrict__ out) {
    const int tid  = threadIdx.x;
    const int wave = tid >> 6;
    const int lane = tid & 63;
    const int j = blockIdx.x * 16 + wave;

    // duplicate label: first i<=j with img row i == row j (hash + verify)
    const u64 hj = hashes[j];
    int cand = BATCH;
    for (int i = lane; i < j; i += 64)
        if (hashes[i] == hj) { cand = i; break; }
    int label = j;
    for (;;) {
        int mm = cand;
#pragma unroll
        for (int s = 32; s; s >>= 1) mm = min(mm, __shfl_xor(mm, s, 64));
        if (mm >= j) break;
        const float4* rpm = (const float4*)(img + (size_t)mm * DIM);
        const float4* rpj = (const float4*)(img + (size_t)j * DIM);
        bool eq = true;
#pragma unroll
        for (int c = 0; c < 3; ++c) {
            float4 vm = rpm[c * 64 + lane];
            float4 vj = rpj[c * 64 + lane];
            eq = eq && (vm.x == vj.x) && (vm.y == vj.y) &&
                 (vm.z == vj.z) && (vm.w == vj.w);
        }
        if (__all(eq)) { label = mm; break; }
        if (cand == mm) {  // hash false positive: owning lane advances
            cand = BATCH;
            for (int i = mm + 64; i < j; i += 64)
                if (hashes[i] == hj) { cand = i; break; }
        }
    }

    // exact fp32 label logit: scale * dot(img[j], txt[label])
    const float4* aj = (const float4*)(img + (size_t)j * DIM);
    const float4* bl = (const float4*)(txt + (size_t)label * DIM);
    float s = 0.0f;
#pragma unroll
    for (int c = 0; c < 3; ++c) {
        const float4 va = aj[c * 64 + lane];
        const float4 vb = bl[c * 64 + lane];
        s += va.x * vb.x + va.y * vb.y + va.z * vb.z + va.w * vb.w;
    }
#pragma unroll
    for (int m = 32; m; m >>= 1) s += __shfl_xor(s, m, 64);

    if (lane == 0) {
        const float lval = scale_p[0] * s;
        const float m0 = pmax[j * 4 + 0], m1 = pmax[j * 4 + 1];
        const float m2 = pmax[j * 4 + 2], m3 = pmax[j * 4 + 3];
        const float gmax = fmaxf(fmaxf(m0, m1), fmaxf(m2, m3));
        const float ss = psum[j * 4 + 0] * __expf(m0 - gmax)
                       + psum[j * 4 + 1] * __expf(m1 - gmax)
                       + psum[j * 4 + 2] * __expf(m2 - gmax)
                       + psum[j * 4 + 3] * __expf(m3 - gmax);
        const float lse = gmax + __logf(ss);
        atomicAdd(acc, lse - lval);   // row loss = lse - label_logit
    }
    __syncthreads();

    if (tid == 0) {
        __threadfence();
        const int old = atomicAdd(counter, 1);
        if (old == (int)gridDim.x - 1) {
            __threadfence();
            out[0] = (*(volatile float*)acc) * (1.0f / BATCH);
        }
    }
}

extern "C" void kernel_launch(void* const* d_in, const int* in_sizes, int n_in,
                              void* d_out, int out_size, void* d_ws, size_t ws_size,
                              hipStream_t stream) {
    const float* img   = (const float*)d_in[0];
    const float* txt   = (const float*)d_in[1];
    const float* scale = (const float*)d_in[2];
    float* out = (float*)d_out;
    char* ws = (char*)d_ws;

    u64*   hashes  = (u64*)ws;
    float* acc     = (float*)(ws + WS_ACC);
    int*   counter = (int*)(ws + WS_ACC + 4);
    float* pmax    = (float*)(ws + WS_PMAX);
    float* psum    = (float*)(ws + WS_PSUM);
    unsigned short* txtB = (unsigned short*)(ws + WS_TXTB);

    prep_kernel<<<256, 256, 0, stream>>>(img, txt, hashes, acc, counter, txtB);
    gemm_kernel<<<256, 1024, 0, stream>>>(img, scale, txtB, pmax, psum);
    final_kernel<<<64, 1024, 0, stream>>>(img, txt, scale, hashes, pmax, psum,
                                          acc, counter, out);
}